// Round 1
// baseline (723.247 us; speedup 1.0000x reference)
//
#include <hip/hip_runtime.h>

#define NN   50000
#define EE   800000
#define MPAD 50048   // 391 * 128

typedef __bf16 bf16x8 __attribute__((ext_vector_type(8)));
typedef float  vfloat4 __attribute__((ext_vector_type(4)));
typedef float  vfloat2 __attribute__((ext_vector_type(2)));
typedef short  vshort2 __attribute__((ext_vector_type(2)));
typedef short  vshort4 __attribute__((ext_vector_type(4)));

__device__ __forceinline__ short f2bf(float f) {
  union { float f; unsigned u; } v; v.f = f;
  unsigned r = v.u + 0x7FFFu + ((v.u >> 16) & 1u);   // RNE
  return (short)(r >> 16);
}
__device__ __forceinline__ float bf2f(short h) {
  union { unsigned u; float f; } v; v.u = ((unsigned)(unsigned short)h) << 16;
  return v.f;
}

__device__ __forceinline__ void load_lds16(const short* g, short* l) {
  __builtin_amdgcn_global_load_lds(
      (__attribute__((address_space(1))) void*)(void*)g,
      (__attribute__((address_space(3))) void*)(void*)l, 16, 0, 0);
}

// ---------------- edge dtype detect (int64 vs int32) ----------------
__global__ __launch_bounds__(256) void detect_kernel(const unsigned* __restrict__ e,
                                                     int* __restrict__ flag) {
  unsigned v = 0;
  for (int i = threadIdx.x; i < 2048; i += 256) v |= e[2 * i + 1];
  for (int o = 32; o; o >>= 1) v |= (unsigned)__shfl_down((int)v, o, 64);
  __shared__ unsigned r[4];
  if ((threadIdx.x & 63) == 0) r[threadIdx.x >> 6] = v;
  __syncthreads();
  if (threadIdx.x == 0) flag[0] = ((r[0] | r[1] | r[2] | r[3]) == 0) ? 1 : 0;
}

// ---------------- CSR build ----------------
__global__ __launch_bounds__(256) void degree_kernel(const void* __restrict__ edges,
                                                     const int* __restrict__ flag,
                                                     int* __restrict__ deg) {
  int e = blockIdx.x * 256 + threadIdx.x;
  if (e >= EE) return;
  int d = flag[0] ? (int)((const long long*)edges)[EE + e] : ((const int*)edges)[EE + e];
  atomicAdd(&deg[d], 1);
}

__global__ __launch_bounds__(1024) void scan_kernel(const int* __restrict__ deg,
                                                    int* __restrict__ offs,
                                                    int* __restrict__ cursor) {
  __shared__ int part[1024];
  int t = threadIdx.x;
  const int C = (NN + 1023) / 1024;
  int lo = t * C, hi = lo + C;
  if (hi > NN) hi = NN;
  if (lo > NN) lo = NN;
  int s = 0;
  for (int i = lo; i < hi; i++) s += deg[i];
  part[t] = s;
  __syncthreads();
  for (int d = 1; d < 1024; d <<= 1) {
    int v = (t >= d) ? part[t - d] : 0;
    __syncthreads();
    part[t] += v;
    __syncthreads();
  }
  int base = (t == 0) ? 0 : part[t - 1];
  for (int i = lo; i < hi; i++) { offs[i] = base; cursor[i] = base; base += deg[i]; }
  if (t == 0) offs[NN] = part[1023];
}

__global__ __launch_bounds__(256) void fill_kernel(const void* __restrict__ edges,
                                                   const int* __restrict__ flag,
                                                   int* __restrict__ cursor,
                                                   int* __restrict__ csr) {
  int e = blockIdx.x * 256 + threadIdx.x;
  if (e >= EE) return;
  int sv, dv;
  if (flag[0]) {
    sv = (int)((const long long*)edges)[e];
    dv = (int)((const long long*)edges)[EE + e];
  } else {
    sv = ((const int*)edges)[e];
    dv = ((const int*)edges)[EE + e];
  }
  int p = atomicAdd(&cursor[dv], 1);
  csr[p] = sv;
}

// ---------------- weight prep: bf16 + transpose (+concat) ----------------
// dst[n*K + k] = bf16( k<K0 ? s0[k][n] : s1[k-K0][n] ),  sX row-major [*][Nc]
__global__ __launch_bounds__(256) void prep_w(const float* __restrict__ s0,
                                              const float* __restrict__ s1,
                                              short* __restrict__ dst,
                                              int K0, int K, int Nc) {
  int idx = blockIdx.x * 256 + threadIdx.x;
  if (idx >= K * Nc) return;
  int n = idx / K, k = idx - n * K;
  float v = (k < K0) ? s0[(size_t)k * Nc + n] : s1[(size_t)(k - K0) * Nc + n];
  dst[idx] = f2bf(v);
}

// ---------------- aggregation (one wave per node) ----------------
__global__ __launch_bounds__(256) void agg1_kernel(const float* __restrict__ x,
                                                   const int* __restrict__ offs,
                                                   const int* __restrict__ csr,
                                                   short* __restrict__ hcat1) {
  int node = blockIdx.x * 4 + (threadIdx.x >> 6);
  int lane = threadIdx.x & 63;
  if (node >= MPAD) return;
  vshort2* row = (vshort2*)(hcat1 + (size_t)node * 256);
  if (node >= NN) { row[lane] = (vshort2){0, 0}; row[64 + lane] = (vshort2){0, 0}; return; }
  int e0 = offs[node], e1 = offs[node + 1];
  float a0 = 0.f, a1 = 0.f;
  for (int e = e0; e < e1; e++) {
    int s = csr[e];
    vfloat2 v = *(const vfloat2*)(x + (size_t)s * 128 + lane * 2);
    a0 += v.x; a1 += v.y;
  }
  float inv = (e1 > e0) ? 1.f / (float)(e1 - e0) : 0.f;
  row[lane] = (vshort2){f2bf(a0 * inv), f2bf(a1 * inv)};
  vfloat2 xv = *(const vfloat2*)(x + (size_t)node * 128 + lane * 2);
  row[64 + lane] = (vshort2){f2bf(xv.x), f2bf(xv.y)};
}

__global__ __launch_bounds__(256) void agg2_kernel(const short* __restrict__ hc,
                                                   const int* __restrict__ offs,
                                                   const int* __restrict__ csr,
                                                   short* __restrict__ hcat2) {
  int node = blockIdx.x * 4 + (threadIdx.x >> 6);
  int lane = threadIdx.x & 63;
  if (node >= MPAD) return;
  vshort4* row = (vshort4*)(hcat2 + (size_t)node * 512);
  if (node >= NN) { row[lane] = (vshort4){0,0,0,0}; row[64 + lane] = (vshort4){0,0,0,0}; return; }
  int e0 = offs[node], e1 = offs[node + 1];
  float a0 = 0.f, a1 = 0.f, a2 = 0.f, a3 = 0.f;
  for (int e = e0; e < e1; e++) {
    int s = csr[e];
    vshort4 v = *(const vshort4*)(hc + (size_t)s * 256 + lane * 4);
    a0 += bf2f(v.x); a1 += bf2f(v.y); a2 += bf2f(v.z); a3 += bf2f(v.w);
  }
  float inv = (e1 > e0) ? 1.f / (float)(e1 - e0) : 0.f;
  row[lane] = (vshort4){f2bf(a0 * inv), f2bf(a1 * inv), f2bf(a2 * inv), f2bf(a3 * inv)};
  row[64 + lane] = *(const vshort4*)(hc + (size_t)node * 256 + lane * 4);
}

// ---------------- graph LayerNorm ----------------
__global__ __launch_bounds__(256) void ln_stats(const float* __restrict__ h,
                                                float* __restrict__ stats, int n4) {
  int stride = gridDim.x * blockDim.x;
  float s = 0.f, s2 = 0.f;
  for (int i = blockIdx.x * blockDim.x + threadIdx.x; i < n4; i += stride) {
    vfloat4 v = *(const vfloat4*)(h + (size_t)i * 4);
    s  += v.x + v.y + v.z + v.w;
    s2 += v.x * v.x + v.y * v.y + v.z * v.z + v.w * v.w;
  }
  for (int o = 32; o; o >>= 1) { s += __shfl_down(s, o, 64); s2 += __shfl_down(s2, o, 64); }
  __shared__ float ps[4], ps2[4];
  int lane = threadIdx.x & 63, wv = threadIdx.x >> 6;
  if (lane == 0) { ps[wv] = s; ps2[wv] = s2; }
  __syncthreads();
  if (threadIdx.x == 0) {
    atomicAdd(&stats[0], ps[0] + ps[1] + ps[2] + ps[3]);
    atomicAdd(&stats[1], ps2[0] + ps2[1] + ps2[2] + ps2[3]);
  }
}

__global__ __launch_bounds__(256) void ln_apply(const float* __restrict__ h,
                                                const float* __restrict__ stats,
                                                const float* __restrict__ w,
                                                const float* __restrict__ b,
                                                short* __restrict__ out,
                                                int realElems, int totElems, int F,
                                                float invCount) {
  int base = (blockIdx.x * blockDim.x + threadIdx.x) * 4;
  if (base >= totElems) return;
  if (base >= realElems) { *(vshort4*)(out + base) = (vshort4){0,0,0,0}; return; }
  float mu  = stats[0] * invCount;
  float var = stats[1] * invCount - mu * mu;
  float rs  = rsqrtf(var + 1e-5f);
  int col = base % F;
  vfloat4 v = *(const vfloat4*)(h + base);
  vshort4 o;
  o.x = f2bf(fmaxf((v.x - mu) * rs * w[col]     + b[col],     0.f));
  o.y = f2bf(fmaxf((v.y - mu) * rs * w[col + 1] + b[col + 1], 0.f));
  o.z = f2bf(fmaxf((v.z - mu) * rs * w[col + 2] + b[col + 2], 0.f));
  o.w = f2bf(fmaxf((v.w - mu) * rs * w[col + 3] + b[col + 3], 0.f));
  *(vshort4*)(out + base) = o;
}

// ---------------- GEMM: C = A(MxK,bf16) * BT(NcxK,bf16)^T + bias ----------------
// m97 structure: 128x128 tile, BK=32, 4 waves, 4x4 of mfma_f32_16x16x32_bf16.
template<int RELU, int OUTBF, int BOUND>
__global__ __launch_bounds__(256) void gemm_bt(const short* __restrict__ A,
                                               const short* __restrict__ BT,
                                               const float* __restrict__ bias,
                                               float* __restrict__ Cf,
                                               short* __restrict__ Cb,
                                               int M, int Nc, int K, int Mreal) {
  __shared__ short lsA[4096];   // 128 rows x 32 k
  __shared__ short lsB[4096];   // 128 n-rows x 32 k
  const int tid  = threadIdx.x;
  const int lane = tid & 63;
  const int wave = tid >> 6;
  const int wr   = (wave >> 1) << 6;
  const int wc   = (wave & 1) << 6;
  const int row0 = blockIdx.y << 7;
  const int col0 = blockIdx.x << 7;
  const int qr   = lane >> 2;          // staging: row within 16-row segment
  const int qc   = (lane & 3) << 3;    // staging: k element offset
  const int r16  = lane & 15;
  const int kq   = (lane >> 4) << 3;   // fragment k offset

  vfloat4 acc[4][4];
#pragma unroll
  for (int i = 0; i < 4; i++)
#pragma unroll
    for (int j = 0; j < 4; j++) acc[i][j] = (vfloat4){0.f, 0.f, 0.f, 0.f};

  const int s0 = wave * 2;
  for (int k0 = 0; k0 < K; k0 += 32) {
    __syncthreads();
#pragma unroll
    for (int t = 0; t < 2; t++) {
      int s = s0 + t;
      int trow = (s << 4) + qr;
      load_lds16(A  + (size_t)(row0 + trow) * K + k0 + qc, lsA + (s << 9) + lane * 8);
      load_lds16(BT + (size_t)(col0 + trow) * K + k0 + qc, lsB + (s << 9) + lane * 8);
    }
    __syncthreads();
    bf16x8 af[4], bfr[4];
#pragma unroll
    for (int i = 0; i < 4; i++) af[i]  = *(const bf16x8*)(lsA + ((wr + (i << 4) + r16) << 5) + kq);
#pragma unroll
    for (int j = 0; j < 4; j++) bfr[j] = *(const bf16x8*)(lsB + ((wc + (j << 4) + r16) << 5) + kq);
#pragma unroll
    for (int i = 0; i < 4; i++)
#pragma unroll
      for (int j = 0; j < 4; j++)
        acc[i][j] = __builtin_amdgcn_mfma_f32_16x16x32_bf16(af[i], bfr[j], acc[i][j], 0, 0, 0);
  }

  const int rq = (lane >> 4) << 2;
#pragma unroll
  for (int i = 0; i < 4; i++) {
#pragma unroll
    for (int j = 0; j < 4; j++) {
#pragma unroll
      for (int p = 0; p < 4; p++) {
        int gr = row0 + wr + (i << 4) + rq + p;
        int gc = col0 + wc + (j << 4) + r16;
        if (BOUND && gr >= Mreal) continue;
        float v = acc[i][j][p] + bias[gc];
        if (RELU) v = fmaxf(v, 0.f);
        if (OUTBF) Cb[(size_t)gr * Nc + gc] = f2bf(v);
        else       Cf[(size_t)gr * Nc + gc] = v;
      }
    }
  }
}

extern "C" void kernel_launch(void* const* d_in, const int* in_sizes, int n_in,
                              void* d_out, int out_size, void* d_ws, size_t ws_size,
                              hipStream_t stream) {
  const float* x    = (const float*)d_in[0];
  const void*  edge = d_in[1];
  const float* Wl1  = (const float*)d_in[2];
  const float* bl1  = (const float*)d_in[3];
  const float* Wr1  = (const float*)d_in[4];
  const float* ln1w = (const float*)d_in[5];
  const float* ln1b = (const float*)d_in[6];
  const float* W1   = (const float*)d_in[7];
  const float* b1   = (const float*)d_in[8];
  const float* W2   = (const float*)d_in[9];
  const float* b2   = (const float*)d_in[10];
  const float* Wl2  = (const float*)d_in[11];
  const float* bl2  = (const float*)d_in[12];
  const float* Wr2  = (const float*)d_in[13];
  const float* ln2w = (const float*)d_in[14];
  const float* ln2b = (const float*)d_in[15];
  const float* W3   = (const float*)d_in[16];
  const float* b3   = (const float*)d_in[17];
  const float* W4   = (const float*)d_in[18];
  const float* b4   = (const float*)d_in[19];
  float* out = (float*)d_out;

  char* wsp = (char*)d_ws;
  size_t o = 0;
  auto alloc = [&](size_t bytes) -> void* {
    void* p = wsp + o;
    o = (o + bytes + 255) & ~(size_t)255;
    return p;
  };
  int*   flag   = (int*)alloc(4);
  int*   deg    = (int*)alloc((size_t)NN * 4);
  int*   offs   = (int*)alloc((size_t)(NN + 1) * 4);
  int*   cursor = (int*)alloc((size_t)NN * 4);
  int*   csr    = (int*)alloc((size_t)EE * 4);
  float* stats  = (float*)alloc(32);
  short* wc1T   = (short*)alloc(256 * 256 * 2);
  short* w1T    = (short*)alloc(512 * 256 * 2);
  short* w2T    = (short*)alloc(256 * 512 * 2);
  short* wc2T   = (short*)alloc(128 * 512 * 2);
  short* w3T    = (short*)alloc(256 * 128 * 2);
  short* w4T    = (short*)alloc(128 * 256 * 2);
  char*  bufB   = (char*)alloc((size_t)MPAD * 512);    // 25.6 MB
  char*  bufA   = (char*)alloc((size_t)MPAD * 1024);   // 51.2 MB
  short* h_e    = (short*)alloc((size_t)MPAD * 128 * 2);

  short* hcat1 = (short*)bufB;   // [agg1 | x]  MPAD x 256 bf16
  float* h1    = (float*)bufA;   // MPAD x 256 f32
  short* h_a   = (short*)bufB;   // MPAD x 256 bf16
  short* h_b   = (short*)bufA;   // MPAD x 512 bf16
  short* h_c   = (short*)bufB;   // MPAD x 256 bf16
  short* hcat2 = (short*)bufA;   // [agg2 | h_c] MPAD x 512 bf16
  float* h_d   = (float*)bufB;   // MPAD x 128 f32
  short* h_f   = (short*)bufA;   // MPAD x 256 bf16

  hipMemsetAsync(deg, 0, (size_t)NN * 4, stream);
  hipMemsetAsync(stats, 0, 32, stream);
  detect_kernel<<<1, 256, 0, stream>>>((const unsigned*)edge, flag);
  degree_kernel<<<(EE + 255) / 256, 256, 0, stream>>>(edge, flag, deg);
  scan_kernel<<<1, 1024, 0, stream>>>(deg, offs, cursor);
  fill_kernel<<<(EE + 255) / 256, 256, 0, stream>>>(edge, flag, cursor, csr);

  prep_w<<<(256 * 256 + 255) / 256, 256, 0, stream>>>(Wl1, Wr1, wc1T, 128, 256, 256);
  prep_w<<<(256 * 512 + 255) / 256, 256, 0, stream>>>(W1, W1, w1T, 256, 256, 512);
  prep_w<<<(512 * 256 + 255) / 256, 256, 0, stream>>>(W2, W2, w2T, 512, 512, 256);
  prep_w<<<(512 * 128 + 255) / 256, 256, 0, stream>>>(Wl2, Wr2, wc2T, 256, 512, 128);
  prep_w<<<(128 * 256 + 255) / 256, 256, 0, stream>>>(W3, W3, w3T, 128, 128, 256);
  prep_w<<<(256 * 128 + 255) / 256, 256, 0, stream>>>(W4, W4, w4T, 256, 256, 128);

  agg1_kernel<<<MPAD / 4, 256, 0, stream>>>(x, offs, csr, hcat1);
  gemm_bt<0, 0, 0><<<dim3(2, MPAD / 128), 256, 0, stream>>>(hcat1, wc1T, bl1, h1, nullptr, MPAD, 256, 256, MPAD);
  ln_stats<<<1024, 256, 0, stream>>>(h1, stats, NN * 256 / 4);
  ln_apply<<<(MPAD * 256 / 4 + 255) / 256, 256, 0, stream>>>(h1, stats, ln1w, ln1b, h_a,
                                                             NN * 256, MPAD * 256, 256, 1.f / (NN * 256.f));
  gemm_bt<1, 1, 0><<<dim3(4, MPAD / 128), 256, 0, stream>>>(h_a, w1T, b1, nullptr, h_b, MPAD, 512, 256, MPAD);
  gemm_bt<1, 1, 0><<<dim3(2, MPAD / 128), 256, 0, stream>>>(h_b, w2T, b2, nullptr, h_c, MPAD, 256, 512, MPAD);
  agg2_kernel<<<MPAD / 4, 256, 0, stream>>>(h_c, offs, csr, hcat2);
  gemm_bt<0, 0, 0><<<dim3(1, MPAD / 128), 256, 0, stream>>>(hcat2, wc2T, bl2, h_d, nullptr, MPAD, 128, 512, MPAD);
  ln_stats<<<1024, 256, 0, stream>>>(h_d, stats + 2, NN * 128 / 4);
  ln_apply<<<(MPAD * 128 / 4 + 255) / 256, 256, 0, stream>>>(h_d, stats + 2, ln2w, ln2b, h_e,
                                                             NN * 128, MPAD * 128, 128, 1.f / (NN * 128.f));
  gemm_bt<1, 1, 0><<<dim3(2, MPAD / 128), 256, 0, stream>>>(h_e, w3T, b3, nullptr, h_f, MPAD, 256, 128, MPAD);
  gemm_bt<0, 0, 1><<<dim3(1, MPAD / 128), 256, 0, stream>>>(h_f, w4T, b4, out, nullptr, MPAD, 128, 256, NN);
}

// Round 2
// 588.559 us; speedup vs baseline: 1.2288x; 1.2288x over previous
//
#include <hip/hip_runtime.h>

#define NN   50000
#define EE   800000
#define MPAD 50048   // 391 * 128
#define NBLK ((NN + 255) / 256)   // 196

typedef __bf16 bf16x8 __attribute__((ext_vector_type(8)));
typedef float  vfloat4 __attribute__((ext_vector_type(4)));
typedef float  vfloat2 __attribute__((ext_vector_type(2)));
typedef short  vshort2 __attribute__((ext_vector_type(2)));
typedef short  vshort4 __attribute__((ext_vector_type(4)));

__device__ __forceinline__ short f2bf(float f) {
  union { float f; unsigned u; } v; v.f = f;
  unsigned r = v.u + 0x7FFFu + ((v.u >> 16) & 1u);   // RNE
  return (short)(r >> 16);
}
__device__ __forceinline__ float bf2f(short h) {
  union { unsigned u; float f; } v; v.u = ((unsigned)(unsigned short)h) << 16;
  return v.f;
}

__device__ __forceinline__ void load_lds16(const short* g, short* l) {
  __builtin_amdgcn_global_load_lds(
      (__attribute__((address_space(1))) void*)(void*)g,
      (__attribute__((address_space(3))) void*)(void*)l, 16, 0, 0);
}

// ---------------- edge dtype detect (int64 vs int32) ----------------
__global__ __launch_bounds__(256) void detect_kernel(const unsigned* __restrict__ e,
                                                     int* __restrict__ flag) {
  unsigned v = 0;
  for (int i = threadIdx.x; i < 2048; i += 256) v |= e[2 * i + 1];
  for (int o = 32; o; o >>= 1) v |= (unsigned)__shfl_down((int)v, o, 64);
  __shared__ unsigned r[4];
  if ((threadIdx.x & 63) == 0) r[threadIdx.x >> 6] = v;
  __syncthreads();
  if (threadIdx.x == 0) flag[0] = ((r[0] | r[1] | r[2] | r[3]) == 0) ? 1 : 0;
}

// ---------------- CSR build ----------------
__global__ __launch_bounds__(256) void degree_kernel(const void* __restrict__ edges,
                                                     const int* __restrict__ flag,
                                                     int* __restrict__ deg) {
  int e = blockIdx.x * 256 + threadIdx.x;
  if (e >= EE) return;
  int d = flag[0] ? (int)((const long long*)edges)[EE + e] : ((const int*)edges)[EE + e];
  atomicAdd(&deg[d], 1);
}

// per-block exclusive scan + block totals (196 blocks x 256)
__global__ __launch_bounds__(256) void scan_local(const int* __restrict__ deg,
                                                  int* __restrict__ iscan,
                                                  int* __restrict__ bsum) {
  __shared__ int tmp[256];
  int t = threadIdx.x;
  int i = blockIdx.x * 256 + t;
  int v = (i < NN) ? deg[i] : 0;
  tmp[t] = v;
  __syncthreads();
  int acc = v;
  for (int d = 1; d < 256; d <<= 1) {
    int u = (t >= d) ? tmp[t - d] : 0;
    __syncthreads();
    acc += u;
    tmp[t] = acc;
    __syncthreads();
  }
  if (i < NN) iscan[i] = acc - v;     // exclusive within block
  if (t == 255) bsum[blockIdx.x] = acc;
}

// each block computes its prefix base from bsum in-LDS, applies it
__global__ __launch_bounds__(256) void scan_apply(const int* __restrict__ iscan,
                                                  const int* __restrict__ bsum,
                                                  int* __restrict__ offs,
                                                  int* __restrict__ cursor) {
  __shared__ int sh[256];
  int t = threadIdx.x;
  int v = (t < NBLK) ? bsum[t] : 0;
  sh[t] = (t < (int)blockIdx.x) ? v : 0;
  __syncthreads();
  for (int d = 128; d; d >>= 1) { if (t < d) sh[t] += sh[t + d]; __syncthreads(); }
  int base = sh[0];
  __syncthreads();
  sh[t] = v;
  __syncthreads();
  for (int d = 128; d; d >>= 1) { if (t < d) sh[t] += sh[t + d]; __syncthreads(); }
  int total = sh[0];
  int i = blockIdx.x * 256 + t;
  if (i < NN) { int off = iscan[i] + base; offs[i] = off; cursor[i] = off; }
  if (blockIdx.x == gridDim.x - 1 && t == 0) offs[NN] = total;
}

__global__ __launch_bounds__(256) void fill_kernel(const void* __restrict__ edges,
                                                   const int* __restrict__ flag,
                                                   int* __restrict__ cursor,
                                                   int* __restrict__ csr) {
  int e = blockIdx.x * 256 + threadIdx.x;
  if (e >= EE) return;
  int sv, dv;
  if (flag[0]) {
    sv = (int)((const long long*)edges)[e];
    dv = (int)((const long long*)edges)[EE + e];
  } else {
    sv = ((const int*)edges)[e];
    dv = ((const int*)edges)[EE + e];
  }
  int p = atomicAdd(&cursor[dv], 1);
  csr[p] = sv;
}

// ---------------- all weight preps in one launch ----------------
// dst[n*K + k] = bf16( k<K0 ? s0[k][n] : s1[k-K0][n] )
__global__ __launch_bounds__(256) void prep_all(
    const float* __restrict__ Wl1, const float* __restrict__ Wr1,
    const float* __restrict__ W1,  const float* __restrict__ W2,
    const float* __restrict__ Wl2, const float* __restrict__ Wr2,
    const float* __restrict__ W3,  const float* __restrict__ W4,
    short* __restrict__ wc1T, short* __restrict__ w1T, short* __restrict__ w2T,
    short* __restrict__ wc2T, short* __restrict__ w3T, short* __restrict__ w4T) {
  int b = blockIdx.x;
  const float *s0, *s1; short* dst; int K0, logK, Nc, base;
  if      (b <  256) { s0=Wl1; s1=Wr1; dst=wc1T; K0=128; logK=8; Nc=256; base=0;    }
  else if (b <  768) { s0=W1;  s1=W1;  dst=w1T;  K0=256; logK=8; Nc=512; base=256;  }
  else if (b < 1280) { s0=W2;  s1=W2;  dst=w2T;  K0=512; logK=9; Nc=256; base=768;  }
  else if (b < 1536) { s0=Wl2; s1=Wr2; dst=wc2T; K0=256; logK=9; Nc=128; base=1280; }
  else if (b < 1664) { s0=W3;  s1=W3;  dst=w3T;  K0=128; logK=7; Nc=256; base=1536; }
  else               { s0=W4;  s1=W4;  dst=w4T;  K0=256; logK=8; Nc=128; base=1664; }
  int idx = (b - base) * 256 + threadIdx.x;
  int n = idx >> logK, k = idx & ((1 << logK) - 1);
  float v = (k < K0) ? s0[(size_t)k * Nc + n] : s1[(size_t)(k - K0) * Nc + n];
  dst[idx] = f2bf(v);
}

// ---------------- aggregation (one wave per node) ----------------
__global__ __launch_bounds__(256) void agg1_kernel(const float* __restrict__ x,
                                                   const int* __restrict__ offs,
                                                   const int* __restrict__ csr,
                                                   short* __restrict__ hcat1) {
  int node = blockIdx.x * 4 + (threadIdx.x >> 6);
  int lane = threadIdx.x & 63;
  if (node >= MPAD) return;
  vshort2* row = (vshort2*)(hcat1 + (size_t)node * 256);
  if (node >= NN) { row[lane] = (vshort2){0, 0}; row[64 + lane] = (vshort2){0, 0}; return; }
  int e0 = offs[node], e1 = offs[node + 1];
  float a0 = 0.f, a1 = 0.f;
  for (int e = e0; e < e1; e++) {
    int s = csr[e];
    vfloat2 v = *(const vfloat2*)(x + (size_t)s * 128 + lane * 2);
    a0 += v.x; a1 += v.y;
  }
  float inv = (e1 > e0) ? 1.f / (float)(e1 - e0) : 0.f;
  row[lane] = (vshort2){f2bf(a0 * inv), f2bf(a1 * inv)};
  vfloat2 xv = *(const vfloat2*)(x + (size_t)node * 128 + lane * 2);
  row[64 + lane] = (vshort2){f2bf(xv.x), f2bf(xv.y)};
}

__global__ __launch_bounds__(256) void agg2_kernel(const short* __restrict__ hc,
                                                   const int* __restrict__ offs,
                                                   const int* __restrict__ csr,
                                                   short* __restrict__ hcat2) {
  int node = blockIdx.x * 4 + (threadIdx.x >> 6);
  int lane = threadIdx.x & 63;
  if (node >= MPAD) return;
  vshort4* row = (vshort4*)(hcat2 + (size_t)node * 512);
  if (node >= NN) { row[lane] = (vshort4){0,0,0,0}; row[64 + lane] = (vshort4){0,0,0,0}; return; }
  int e0 = offs[node], e1 = offs[node + 1];
  float a0 = 0.f, a1 = 0.f, a2 = 0.f, a3 = 0.f;
  for (int e = e0; e < e1; e++) {
    int s = csr[e];
    vshort4 v = *(const vshort4*)(hc + (size_t)s * 256 + lane * 4);
    a0 += bf2f(v.x); a1 += bf2f(v.y); a2 += bf2f(v.z); a3 += bf2f(v.w);
  }
  float inv = (e1 > e0) ? 1.f / (float)(e1 - e0) : 0.f;
  row[lane] = (vshort4){f2bf(a0 * inv), f2bf(a1 * inv), f2bf(a2 * inv), f2bf(a3 * inv)};
  row[64 + lane] = *(const vshort4*)(hc + (size_t)node * 256 + lane * 4);
}

// ---------------- graph LayerNorm apply ----------------
__global__ __launch_bounds__(256) void ln_apply(const float* __restrict__ h,
                                                const float* __restrict__ stats,
                                                const float* __restrict__ w,
                                                const float* __restrict__ b,
                                                short* __restrict__ out,
                                                int realElems, int totElems, int F,
                                                float invCount) {
  int base = (blockIdx.x * blockDim.x + threadIdx.x) * 4;
  if (base >= totElems) return;
  if (base >= realElems) { *(vshort4*)(out + base) = (vshort4){0,0,0,0}; return; }
  float mu  = stats[0] * invCount;
  float var = stats[1] * invCount - mu * mu;
  float rs  = rsqrtf(var + 1e-5f);
  int col = base % F;
  vfloat4 v = *(const vfloat4*)(h + base);
  vshort4 o;
  o.x = f2bf(fmaxf((v.x - mu) * rs * w[col]     + b[col],     0.f));
  o.y = f2bf(fmaxf((v.y - mu) * rs * w[col + 1] + b[col + 1], 0.f));
  o.z = f2bf(fmaxf((v.z - mu) * rs * w[col + 2] + b[col + 2], 0.f));
  o.w = f2bf(fmaxf((v.w - mu) * rs * w[col + 3] + b[col + 3], 0.f));
  *(vshort4*)(out + base) = o;
}

// ---------------- GEMM: C = A(MxK,bf16) * BT(NcxK,bf16)^T + bias ----------------
// m97 structure: 128x128 tile, BK=32, 4 waves, 4x4 of mfma_f32_16x16x32_bf16.
// STATS=1 fuses graph-LN sum/sumsq (over rows < Mreal, pre-ReLU) via 2 atomics/block.
template<int RELU, int OUTBF, int BOUND, int STATS>
__global__ __launch_bounds__(256) void gemm_bt(const short* __restrict__ A,
                                               const short* __restrict__ BT,
                                               const float* __restrict__ bias,
                                               float* __restrict__ Cf,
                                               short* __restrict__ Cb,
                                               float* __restrict__ statsOut,
                                               int M, int Nc, int K, int Mreal) {
  __shared__ short lsA[4096];   // 128 rows x 32 k
  __shared__ short lsB[4096];   // 128 n-rows x 32 k
  const int tid  = threadIdx.x;
  const int lane = tid & 63;
  const int wave = tid >> 6;
  const int wr   = (wave >> 1) << 6;
  const int wc   = (wave & 1) << 6;
  const int row0 = blockIdx.y << 7;
  const int col0 = blockIdx.x << 7;
  const int qr   = lane >> 2;
  const int qc   = (lane & 3) << 3;
  const int r16  = lane & 15;
  const int kq   = (lane >> 4) << 3;

  vfloat4 acc[4][4];
#pragma unroll
  for (int i = 0; i < 4; i++)
#pragma unroll
    for (int j = 0; j < 4; j++) acc[i][j] = (vfloat4){0.f, 0.f, 0.f, 0.f};

  const int s0 = wave * 2;
  for (int k0 = 0; k0 < K; k0 += 32) {
    __syncthreads();
#pragma unroll
    for (int t = 0; t < 2; t++) {
      int s = s0 + t;
      int trow = (s << 4) + qr;
      load_lds16(A  + (size_t)(row0 + trow) * K + k0 + qc, lsA + (s << 9) + lane * 8);
      load_lds16(BT + (size_t)(col0 + trow) * K + k0 + qc, lsB + (s << 9) + lane * 8);
    }
    __syncthreads();
    bf16x8 af[4], bfr[4];
#pragma unroll
    for (int i = 0; i < 4; i++) af[i]  = *(const bf16x8*)(lsA + ((wr + (i << 4) + r16) << 5) + kq);
#pragma unroll
    for (int j = 0; j < 4; j++) bfr[j] = *(const bf16x8*)(lsB + ((wc + (j << 4) + r16) << 5) + kq);
#pragma unroll
    for (int i = 0; i < 4; i++)
#pragma unroll
      for (int j = 0; j < 4; j++)
        acc[i][j] = __builtin_amdgcn_mfma_f32_16x16x32_bf16(af[i], bfr[j], acc[i][j], 0, 0, 0);
  }

  const int rq = (lane >> 4) << 2;
  float s = 0.f, s2 = 0.f;
#pragma unroll
  for (int i = 0; i < 4; i++) {
#pragma unroll
    for (int j = 0; j < 4; j++) {
#pragma unroll
      for (int p = 0; p < 4; p++) {
        int gr = row0 + wr + (i << 4) + rq + p;
        int gc = col0 + wc + (j << 4) + r16;
        if (BOUND && gr >= Mreal) continue;
        float v = acc[i][j][p] + bias[gc];
        if (STATS) { s += v; s2 += v * v; }
        if (RELU) v = fmaxf(v, 0.f);
        if (OUTBF) Cb[(size_t)gr * Nc + gc] = f2bf(v);
        else       Cf[(size_t)gr * Nc + gc] = v;
      }
    }
  }
  if (STATS) {
    for (int o2 = 32; o2; o2 >>= 1) {
      s  += __shfl_down(s,  o2, 64);
      s2 += __shfl_down(s2, o2, 64);
    }
    __shared__ float ps[8];
    if (lane == 0) { ps[wave] = s; ps[wave + 4] = s2; }
    __syncthreads();
    if (tid == 0) {
      atomicAdd(&statsOut[0], ps[0] + ps[1] + ps[2] + ps[3]);
      atomicAdd(&statsOut[1], ps[4] + ps[5] + ps[6] + ps[7]);
    }
  }
}

extern "C" void kernel_launch(void* const* d_in, const int* in_sizes, int n_in,
                              void* d_out, int out_size, void* d_ws, size_t ws_size,
                              hipStream_t stream) {
  const float* x    = (const float*)d_in[0];
  const void*  edge = d_in[1];
  const float* Wl1  = (const float*)d_in[2];
  const float* bl1  = (const float*)d_in[3];
  const float* Wr1  = (const float*)d_in[4];
  const float* ln1w = (const float*)d_in[5];
  const float* ln1b = (const float*)d_in[6];
  const float* W1   = (const float*)d_in[7];
  const float* b1   = (const float*)d_in[8];
  const float* W2   = (const float*)d_in[9];
  const float* b2   = (const float*)d_in[10];
  const float* Wl2  = (const float*)d_in[11];
  const float* bl2  = (const float*)d_in[12];
  const float* Wr2  = (const float*)d_in[13];
  const float* ln2w = (const float*)d_in[14];
  const float* ln2b = (const float*)d_in[15];
  const float* W3   = (const float*)d_in[16];
  const float* b3   = (const float*)d_in[17];
  const float* W4   = (const float*)d_in[18];
  const float* b4   = (const float*)d_in[19];
  float* out = (float*)d_out;

  char* wsp = (char*)d_ws;
  size_t o = 0;
  auto alloc = [&](size_t bytes) -> void* {
    void* p = wsp + o;
    o = (o + bytes + 255) & ~(size_t)255;
    return p;
  };
  int*   flag   = (int*)alloc(4);
  int*   deg    = (int*)alloc((size_t)NN * 4);
  int*   iscan  = (int*)alloc((size_t)NN * 4);
  int*   bsum   = (int*)alloc((size_t)NBLK * 4);
  int*   offs   = (int*)alloc((size_t)(NN + 1) * 4);
  int*   cursor = (int*)alloc((size_t)NN * 4);
  int*   csr    = (int*)alloc((size_t)EE * 4);
  float* stats  = (float*)alloc(32);
  short* wc1T   = (short*)alloc(256 * 256 * 2);
  short* w1T    = (short*)alloc(512 * 256 * 2);
  short* w2T    = (short*)alloc(256 * 512 * 2);
  short* wc2T   = (short*)alloc(128 * 512 * 2);
  short* w3T    = (short*)alloc(256 * 128 * 2);
  short* w4T    = (short*)alloc(128 * 256 * 2);
  char*  bufB   = (char*)alloc((size_t)MPAD * 512);    // 25.6 MB
  char*  bufA   = (char*)alloc((size_t)MPAD * 1024);   // 51.2 MB
  short* h_e    = (short*)alloc((size_t)MPAD * 128 * 2);

  short* hcat1 = (short*)bufB;   // [agg1 | x]  MPAD x 256 bf16
  float* h1    = (float*)bufA;   // MPAD x 256 f32
  short* h_a   = (short*)bufB;   // MPAD x 256 bf16
  short* h_b   = (short*)bufA;   // MPAD x 512 bf16
  short* h_c   = (short*)bufB;   // MPAD x 256 bf16
  short* hcat2 = (short*)bufA;   // [agg2 | h_c] MPAD x 512 bf16
  float* h_d   = (float*)bufB;   // MPAD x 128 f32
  short* h_f   = (short*)bufA;   // MPAD x 256 bf16

  hipMemsetAsync(deg, 0, (size_t)NN * 4, stream);
  hipMemsetAsync(stats, 0, 32, stream);
  detect_kernel<<<1, 256, 0, stream>>>((const unsigned*)edge, flag);
  degree_kernel<<<(EE + 255) / 256, 256, 0, stream>>>(edge, flag, deg);
  scan_local<<<NBLK, 256, 0, stream>>>(deg, iscan, bsum);
  scan_apply<<<NBLK, 256, 0, stream>>>(iscan, bsum, offs, cursor);
  fill_kernel<<<(EE + 255) / 256, 256, 0, stream>>>(edge, flag, cursor, csr);

  prep_all<<<1792, 256, 0, stream>>>(Wl1, Wr1, W1, W2, Wl2, Wr2, W3, W4,
                                     wc1T, w1T, w2T, wc2T, w3T, w4T);

  agg1_kernel<<<MPAD / 4, 256, 0, stream>>>(x, offs, csr, hcat1);
  gemm_bt<0, 0, 1, 1><<<dim3(2, MPAD / 128), 256, 0, stream>>>(hcat1, wc1T, bl1, h1, nullptr, stats, MPAD, 256, 256, NN);
  ln_apply<<<(MPAD * 256 / 4 + 255) / 256, 256, 0, stream>>>(h1, stats, ln1w, ln1b, h_a,
                                                             NN * 256, MPAD * 256, 256, 1.f / (NN * 256.f));
  gemm_bt<1, 1, 0, 0><<<dim3(4, MPAD / 128), 256, 0, stream>>>(h_a, w1T, b1, nullptr, h_b, nullptr, MPAD, 512, 256, MPAD);
  gemm_bt<1, 1, 0, 0><<<dim3(2, MPAD / 128), 256, 0, stream>>>(h_b, w2T, b2, nullptr, h_c, nullptr, MPAD, 256, 512, MPAD);
  agg2_kernel<<<MPAD / 4, 256, 0, stream>>>(h_c, offs, csr, hcat2);
  gemm_bt<0, 0, 1, 1><<<dim3(1, MPAD / 128), 256, 0, stream>>>(hcat2, wc2T, bl2, h_d, nullptr, stats + 2, MPAD, 128, 512, NN);
  ln_apply<<<(MPAD * 128 / 4 + 255) / 256, 256, 0, stream>>>(h_d, stats + 2, ln2w, ln2b, h_e,
                                                             NN * 128, MPAD * 128, 128, 1.f / (NN * 128.f));
  gemm_bt<1, 1, 0, 0><<<dim3(2, MPAD / 128), 256, 0, stream>>>(h_e, w3T, b3, nullptr, h_f, nullptr, MPAD, 256, 128, MPAD);
  gemm_bt<0, 0, 1, 0><<<dim3(1, MPAD / 128), 256, 0, stream>>>(h_f, w4T, b4, out, nullptr, nullptr, MPAD, 128, 256, NN);
}

// Round 5
// 518.835 us; speedup vs baseline: 1.3940x; 1.1344x over previous
//
#include <hip/hip_runtime.h>

#define NN   50000
#define EE   800000
#define MPAD 50048   // 391 * 128
#define NBLK ((NN + 255) / 256)   // 196

typedef __bf16 bf16x8 __attribute__((ext_vector_type(8)));
typedef float  vfloat4 __attribute__((ext_vector_type(4)));
typedef float  vfloat2 __attribute__((ext_vector_type(2)));
typedef short  vshort2 __attribute__((ext_vector_type(2)));
typedef short  vshort4 __attribute__((ext_vector_type(4)));
typedef short  vshort8 __attribute__((ext_vector_type(8)));

__device__ __forceinline__ short f2bf(float f) {
  union { float f; unsigned u; } v; v.f = f;
  unsigned r = v.u + 0x7FFFu + ((v.u >> 16) & 1u);   // RNE
  return (short)(r >> 16);
}
__device__ __forceinline__ float bf2f(short h) {
  union { unsigned u; float f; } v; v.u = ((unsigned)(unsigned short)h) << 16;
  return v.f;
}

__device__ __forceinline__ void load_lds16(const short* g, short* l) {
  __builtin_amdgcn_global_load_lds(
      (__attribute__((address_space(1))) void*)(void*)g,
      (__attribute__((address_space(3))) void*)(void*)l, 16, 0, 0);
}

// ---------------- edge dtype detect (int64 vs int32) ----------------
__global__ __launch_bounds__(256) void detect_kernel(const unsigned* __restrict__ e,
                                                     int* __restrict__ flag) {
  unsigned v = 0;
  for (int i = threadIdx.x; i < 2048; i += 256) v |= e[2 * i + 1];
  for (int o = 32; o; o >>= 1) v |= (unsigned)__shfl_down((int)v, o, 64);
  __shared__ unsigned r[4];
  if ((threadIdx.x & 63) == 0) r[threadIdx.x >> 6] = v;
  __syncthreads();
  if (threadIdx.x == 0) flag[0] = ((r[0] | r[1] | r[2] | r[3]) == 0) ? 1 : 0;
}

// ---------------- CSR build ----------------
__global__ __launch_bounds__(256) void degree_kernel(const void* __restrict__ edges,
                                                     const int* __restrict__ flag,
                                                     int* __restrict__ deg) {
  int e = blockIdx.x * 256 + threadIdx.x;
  if (e >= EE) return;
  int d = flag[0] ? (int)((const long long*)edges)[EE + e] : ((const int*)edges)[EE + e];
  atomicAdd(&deg[d], 1);
}

// per-block exclusive scan + block totals (196 blocks x 256)
__global__ __launch_bounds__(256) void scan_local(const int* __restrict__ deg,
                                                  int* __restrict__ iscan,
                                                  int* __restrict__ bsum) {
  __shared__ int tmp[256];
  int t = threadIdx.x;
  int i = blockIdx.x * 256 + t;
  int v = (i < NN) ? deg[i] : 0;
  tmp[t] = v;
  __syncthreads();
  int acc = v;
  for (int d = 1; d < 256; d <<= 1) {
    int u = (t >= d) ? tmp[t - d] : 0;
    __syncthreads();
    acc += u;
    tmp[t] = acc;
    __syncthreads();
  }
  if (i < NN) iscan[i] = acc - v;     // exclusive within block
  if (t == 255) bsum[blockIdx.x] = acc;
}

// each block computes its prefix base from bsum in-LDS, applies it
__global__ __launch_bounds__(256) void scan_apply(const int* __restrict__ iscan,
                                                  const int* __restrict__ bsum,
                                                  int* __restrict__ offs,
                                                  int* __restrict__ cursor) {
  __shared__ int sh[256];
  int t = threadIdx.x;
  int v = (t < NBLK) ? bsum[t] : 0;
  sh[t] = (t < (int)blockIdx.x) ? v : 0;
  __syncthreads();
  for (int d = 128; d; d >>= 1) { if (t < d) sh[t] += sh[t + d]; __syncthreads(); }
  int base = sh[0];
  __syncthreads();
  sh[t] = v;
  __syncthreads();
  for (int d = 128; d; d >>= 1) { if (t < d) sh[t] += sh[t + d]; __syncthreads(); }
  int total = sh[0];
  int i = blockIdx.x * 256 + t;
  if (i < NN) { int off = iscan[i] + base; offs[i] = off; cursor[i] = off; }
  if (blockIdx.x == gridDim.x - 1 && t == 0) offs[NN] = total;
}

__global__ __launch_bounds__(256) void fill_kernel(const void* __restrict__ edges,
                                                   const int* __restrict__ flag,
                                                   int* __restrict__ cursor,
                                                   int* __restrict__ csr) {
  int e = blockIdx.x * 256 + threadIdx.x;
  if (e >= EE) return;
  int sv, dv;
  if (flag[0]) {
    sv = (int)((const long long*)edges)[e];
    dv = (int)((const long long*)edges)[EE + e];
  } else {
    sv = ((const int*)edges)[e];
    dv = ((const int*)edges)[EE + e];
  }
  int p = atomicAdd(&cursor[dv], 1);
  csr[p] = sv;
}

// ---------------- x -> bf16 cast (NN x 128) ----------------
__global__ __launch_bounds__(256) void xcast_kernel(const float* __restrict__ x,
                                                    short* __restrict__ xbf) {
  int i = blockIdx.x * 256 + threadIdx.x;   // one per 8 elems
  if (i >= NN * 128 / 8) return;
  vfloat4 v0 = *(const vfloat4*)(x + (size_t)i * 8);
  vfloat4 v1 = *(const vfloat4*)(x + (size_t)i * 8 + 4);
  vshort8 o;
  o[0] = f2bf(v0.x); o[1] = f2bf(v0.y); o[2] = f2bf(v0.z); o[3] = f2bf(v0.w);
  o[4] = f2bf(v1.x); o[5] = f2bf(v1.y); o[6] = f2bf(v1.z); o[7] = f2bf(v1.w);
  *(vshort8*)(xbf + (size_t)i * 8) = o;
}

// ---------------- all weight preps in one launch ----------------
__global__ __launch_bounds__(256) void prep_all(
    const float* __restrict__ Wl1, const float* __restrict__ Wr1,
    const float* __restrict__ W1,  const float* __restrict__ W2,
    const float* __restrict__ Wl2, const float* __restrict__ Wr2,
    const float* __restrict__ W3,  const float* __restrict__ W4,
    short* __restrict__ wc1T, short* __restrict__ w1T, short* __restrict__ w2T,
    short* __restrict__ wc2T, short* __restrict__ w3T, short* __restrict__ w4T) {
  int b = blockIdx.x;
  const float *s0, *s1; short* dst; int K0, logK, Nc, base;
  if      (b <  256) { s0=Wl1; s1=Wr1; dst=wc1T; K0=128; logK=8; Nc=256; base=0;    }
  else if (b <  768) { s0=W1;  s1=W1;  dst=w1T;  K0=256; logK=8; Nc=512; base=256;  }
  else if (b < 1280) { s0=W2;  s1=W2;  dst=w2T;  K0=512; logK=9; Nc=256; base=768;  }
  else if (b < 1536) { s0=Wl2; s1=Wr2; dst=wc2T; K0=256; logK=9; Nc=128; base=1280; }
  else if (b < 1664) { s0=W3;  s1=W3;  dst=w3T;  K0=128; logK=7; Nc=256; base=1536; }
  else               { s0=W4;  s1=W4;  dst=w4T;  K0=256; logK=8; Nc=128; base=1664; }
  int idx = (b - base) * 256 + threadIdx.x;
  int n = idx >> logK, k = idx & ((1 << logK) - 1);
  float v = (k < K0) ? s0[(size_t)k * Nc + n] : s1[(size_t)(k - K0) * Nc + n];
  dst[idx] = f2bf(v);
}

// ---------------- aggregation 1: gather bf16 x rows (256 B) ----------------
// 1 wave/node; 4 lane-groups of 16 gather concurrently.
// R4 post-mortem: __shfl inside group-divergent loops read INACTIVE source
// lanes (ds_bpermute gives undefined data) -> wrong gather indices. Fix:
// wave-uniform loop bound; all shfls run with full wave active; only the
// load+accumulate is predicated (no shfl inside divergent code).
__global__ __launch_bounds__(256) void agg1_kernel(const short* __restrict__ xbf,
                                                   const int* __restrict__ offs,
                                                   const int* __restrict__ csr,
                                                   short* __restrict__ hcat1) {
  int node = blockIdx.x * 4 + (threadIdx.x >> 6);
  int lane = threadIdx.x & 63;
  if (node >= MPAD) return;
  short* row = hcat1 + (size_t)node * 256;
  if (node >= NN) { *(vshort4*)(row + lane * 4) = (vshort4){0, 0, 0, 0}; return; }
  int g = lane >> 4, sub = lane & 15;
  int e0 = offs[node], e1 = offs[node + 1];
  float a0[8] = {0, 0, 0, 0, 0, 0, 0, 0};
  float a1[8] = {0, 0, 0, 0, 0, 0, 0, 0};
  int e = e0;
  while (e < e1) {                         // wave-uniform
    int cnt = e1 - e; if (cnt > 64) cnt = 64;
    int myidx = (lane < cnt) ? csr[e + lane] : 0;
    for (int i = 0; i < cnt; i += 8) {     // wave-uniform bound
      int p0 = g + i;                      // <= 59
      int p1 = g + i + 4;                  // <= 63
      int s0 = __shfl(myidx, p0, 64);      // full wave active
      int s1 = __shfl(myidx, p1, 64);
      if (p0 < cnt) {
        vshort8 v0 = *(const vshort8*)(xbf + (size_t)s0 * 128 + sub * 8);
#pragma unroll
        for (int j = 0; j < 8; j++) a0[j] += bf2f(v0[j]);
      }
      if (p1 < cnt) {
        vshort8 v1 = *(const vshort8*)(xbf + (size_t)s1 * 128 + sub * 8);
#pragma unroll
        for (int j = 0; j < 8; j++) a1[j] += bf2f(v1[j]);
      }
    }
    e += cnt;
  }
#pragma unroll
  for (int j = 0; j < 8; j++) {
    a0[j] += a1[j];
    a0[j] += __shfl_down(a0[j], 32, 64);
    a0[j] += __shfl_down(a0[j], 16, 64);
  }
  float inv = (e1 > e0) ? 1.f / (float)(e1 - e0) : 0.f;
  if (g == 0) {
    vshort8 o;
#pragma unroll
    for (int j = 0; j < 8; j++) o[j] = f2bf(a0[j] * inv);
    *(vshort8*)(row + sub * 8) = o;
  } else if (g == 1) {
    *(vshort8*)(row + 128 + sub * 8) = *(const vshort8*)(xbf + (size_t)node * 128 + sub * 8);
  }
}

// ---------------- aggregation 2: gather bf16 h rows (512 B) ----------------
// 1 wave/node; 2 lane-groups of 32. Same uniform-shfl structure as agg1.
__global__ __launch_bounds__(256) void agg2_kernel(const short* __restrict__ hc,
                                                   const int* __restrict__ offs,
                                                   const int* __restrict__ csr,
                                                   short* __restrict__ hcat2) {
  int node = blockIdx.x * 4 + (threadIdx.x >> 6);
  int lane = threadIdx.x & 63;
  if (node >= MPAD) return;
  short* row = hcat2 + (size_t)node * 512;
  if (node >= NN) { *(vshort8*)(row + lane * 8) = (vshort8){0,0,0,0,0,0,0,0}; return; }
  int g = lane >> 5, sub = lane & 31;
  int e0 = offs[node], e1 = offs[node + 1];
  float a0[8] = {0,0,0,0,0,0,0,0}, a1[8] = {0,0,0,0,0,0,0,0};
  float a2[8] = {0,0,0,0,0,0,0,0}, a3[8] = {0,0,0,0,0,0,0,0};
  int e = e0;
  while (e < e1) {                         // wave-uniform
    int cnt = e1 - e; if (cnt > 64) cnt = 64;
    int myidx = (lane < cnt) ? csr[e + lane] : 0;
    for (int i = 0; i < cnt; i += 8) {     // wave-uniform bound
      int p0 = g + i;                      // <= 57
      int p1 = g + i + 2;
      int p2 = g + i + 4;
      int p3 = g + i + 6;                  // <= 63
      int s0 = __shfl(myidx, p0, 64);      // full wave active
      int s1 = __shfl(myidx, p1, 64);
      int s2 = __shfl(myidx, p2, 64);
      int s3 = __shfl(myidx, p3, 64);
      if (p0 < cnt) {
        vshort8 v = *(const vshort8*)(hc + (size_t)s0 * 256 + sub * 8);
#pragma unroll
        for (int j = 0; j < 8; j++) a0[j] += bf2f(v[j]);
      }
      if (p1 < cnt) {
        vshort8 v = *(const vshort8*)(hc + (size_t)s1 * 256 + sub * 8);
#pragma unroll
        for (int j = 0; j < 8; j++) a1[j] += bf2f(v[j]);
      }
      if (p2 < cnt) {
        vshort8 v = *(const vshort8*)(hc + (size_t)s2 * 256 + sub * 8);
#pragma unroll
        for (int j = 0; j < 8; j++) a2[j] += bf2f(v[j]);
      }
      if (p3 < cnt) {
        vshort8 v = *(const vshort8*)(hc + (size_t)s3 * 256 + sub * 8);
#pragma unroll
        for (int j = 0; j < 8; j++) a3[j] += bf2f(v[j]);
      }
    }
    e += cnt;
  }
#pragma unroll
  for (int j = 0; j < 8; j++) {
    a0[j] += a1[j] + a2[j] + a3[j];
    a0[j] += __shfl_down(a0[j], 32, 64);
  }
  float inv = (e1 > e0) ? 1.f / (float)(e1 - e0) : 0.f;
  if (g == 0) {
    vshort8 o;
#pragma unroll
    for (int j = 0; j < 8; j++) o[j] = f2bf(a0[j] * inv);
    *(vshort8*)(row + sub * 8) = o;
  } else {
    *(vshort8*)(row + 256 + sub * 8) = *(const vshort8*)(hc + (size_t)node * 256 + sub * 8);
  }
}

// ---------------- graph LayerNorm apply ----------------
__global__ __launch_bounds__(256) void ln_apply(const float* __restrict__ h,
                                                const float* __restrict__ stats,
                                                const float* __restrict__ w,
                                                const float* __restrict__ b,
                                                short* __restrict__ out,
                                                int realElems, int totElems, int F,
                                                float invCount) {
  int base = (blockIdx.x * blockDim.x + threadIdx.x) * 4;
  if (base >= totElems) return;
  if (base >= realElems) { *(vshort4*)(out + base) = (vshort4){0,0,0,0}; return; }
  float mu  = stats[0] * invCount;
  float var = stats[1] * invCount - mu * mu;
  float rs  = rsqrtf(var + 1e-5f);
  int col = base % F;
  vfloat4 v = *(const vfloat4*)(h + base);
  vshort4 o;
  o.x = f2bf(fmaxf((v.x - mu) * rs * w[col]     + b[col],     0.f));
  o.y = f2bf(fmaxf((v.y - mu) * rs * w[col + 1] + b[col + 1], 0.f));
  o.z = f2bf(fmaxf((v.z - mu) * rs * w[col + 2] + b[col + 2], 0.f));
  o.w = f2bf(fmaxf((v.w - mu) * rs * w[col + 3] + b[col + 3], 0.f));
  *(vshort4*)(out + base) = o;
}

// ---------------- GEMM: C = A(MxK,bf16) * BT(NcxK,bf16)^T + bias ----------------
template<int RELU, int OUTBF, int BOUND, int STATS>
__global__ __launch_bounds__(256) void gemm_bt(const short* __restrict__ A,
                                               const short* __restrict__ BT,
                                               const float* __restrict__ bias,
                                               float* __restrict__ Cf,
                                               short* __restrict__ Cb,
                                               float* __restrict__ statsOut,
                                               int M, int Nc, int K, int Mreal) {
  __shared__ short lsA[4096];   // 128 rows x 32 k
  __shared__ short lsB[4096];   // 128 n-rows x 32 k
  const int tid  = threadIdx.x;
  const int lane = tid & 63;
  const int wave = tid >> 6;
  const int wr   = (wave >> 1) << 6;
  const int wc   = (wave & 1) << 6;
  const int row0 = blockIdx.y << 7;
  const int col0 = blockIdx.x << 7;
  const int qr   = lane >> 2;
  const int qc   = (lane & 3) << 3;
  const int r16  = lane & 15;
  const int kq   = (lane >> 4) << 3;

  vfloat4 acc[4][4];
#pragma unroll
  for (int i = 0; i < 4; i++)
#pragma unroll
    for (int j = 0; j < 4; j++) acc[i][j] = (vfloat4){0.f, 0.f, 0.f, 0.f};

  const int s0 = wave * 2;
  for (int k0 = 0; k0 < K; k0 += 32) {
    __syncthreads();
#pragma unroll
    for (int t = 0; t < 2; t++) {
      int s = s0 + t;
      int trow = (s << 4) + qr;
      load_lds16(A  + (size_t)(row0 + trow) * K + k0 + qc, lsA + (s << 9) + lane * 8);
      load_lds16(BT + (size_t)(col0 + trow) * K + k0 + qc, lsB + (s << 9) + lane * 8);
    }
    __syncthreads();
    bf16x8 af[4], bfr[4];
#pragma unroll
    for (int i = 0; i < 4; i++) af[i]  = *(const bf16x8*)(lsA + ((wr + (i << 4) + r16) << 5) + kq);
#pragma unroll
    for (int j = 0; j < 4; j++) bfr[j] = *(const bf16x8*)(lsB + ((wc + (j << 4) + r16) << 5) + kq);
#pragma unroll
    for (int i = 0; i < 4; i++)
#pragma unroll
      for (int j = 0; j < 4; j++)
        acc[i][j] = __builtin_amdgcn_mfma_f32_16x16x32_bf16(af[i], bfr[j], acc[i][j], 0, 0, 0);
  }

  const int rq = (lane >> 4) << 2;
  float s = 0.f, s2 = 0.f;
#pragma unroll
  for (int i = 0; i < 4; i++) {
#pragma unroll
    for (int j = 0; j < 4; j++) {
#pragma unroll
      for (int p = 0; p < 4; p++) {
        int gr = row0 + wr + (i << 4) + rq + p;
        int gc = col0 + wc + (j << 4) + r16;
        if (BOUND && gr >= Mreal) continue;
        float v = acc[i][j][p] + bias[gc];
        if (STATS) { s += v; s2 += v * v; }
        if (RELU) v = fmaxf(v, 0.f);
        if (OUTBF) Cb[(size_t)gr * Nc + gc] = f2bf(v);
        else       Cf[(size_t)gr * Nc + gc] = v;
      }
    }
  }
  if (STATS) {
    for (int o2 = 32; o2; o2 >>= 1) {
      s  += __shfl_down(s,  o2, 64);
      s2 += __shfl_down(s2, o2, 64);
    }
    __shared__ float ps[8];
    if (lane == 0) { ps[wave] = s; ps[wave + 4] = s2; }
    __syncthreads();
    if (tid == 0) {
      atomicAdd(&statsOut[0], ps[0] + ps[1] + ps[2] + ps[3]);
      atomicAdd(&statsOut[1], ps[4] + ps[5] + ps[6] + ps[7]);
    }
  }
}

extern "C" void kernel_launch(void* const* d_in, const int* in_sizes, int n_in,
                              void* d_out, int out_size, void* d_ws, size_t ws_size,
                              hipStream_t stream) {
  const float* x    = (const float*)d_in[0];
  const void*  edge = d_in[1];
  const float* Wl1  = (const float*)d_in[2];
  const float* bl1  = (const float*)d_in[3];
  const float* Wr1  = (const float*)d_in[4];
  const float* ln1w = (const float*)d_in[5];
  const float* ln1b = (const float*)d_in[6];
  const float* W1   = (const float*)d_in[7];
  const float* b1   = (const float*)d_in[8];
  const float* W2   = (const float*)d_in[9];
  const float* b2   = (const float*)d_in[10];
  const float* Wl2  = (const float*)d_in[11];
  const float* bl2  = (const float*)d_in[12];
  const float* Wr2  = (const float*)d_in[13];
  const float* ln2w = (const float*)d_in[14];
  const float* ln2b = (const float*)d_in[15];
  const float* W3   = (const float*)d_in[16];
  const float* b3   = (const float*)d_in[17];
  const float* W4   = (const float*)d_in[18];
  const float* b4   = (const float*)d_in[19];
  float* out = (float*)d_out;

  char* wsp = (char*)d_ws;
  size_t o = 0;
  auto alloc = [&](size_t bytes) -> void* {
    void* p = wsp + o;
    o = (o + bytes + 255) & ~(size_t)255;
    return p;
  };
  // Footprint ~82 MB (< R2's proven-safe 94.6 MB). xbf/h_e aliased into bufA.
  int*   flag   = (int*)alloc(4);
  int*   deg    = (int*)alloc((size_t)NN * 4);
  int*   iscan  = (int*)alloc((size_t)NN * 4);
  int*   bsum   = (int*)alloc((size_t)NBLK * 4);
  int*   offs   = (int*)alloc((size_t)(NN + 1) * 4);
  int*   cursor = (int*)alloc((size_t)NN * 4);
  int*   csr    = (int*)alloc((size_t)EE * 4);
  float* stats  = (float*)alloc(32);
  short* wc1T   = (short*)alloc(256 * 256 * 2);
  short* w1T    = (short*)alloc(512 * 256 * 2);
  short* w2T    = (short*)alloc(256 * 512 * 2);
  short* wc2T   = (short*)alloc(128 * 512 * 2);
  short* w3T    = (short*)alloc(256 * 128 * 2);
  short* w4T    = (short*)alloc(128 * 256 * 2);
  char*  bufB   = (char*)alloc((size_t)MPAD * 512);    // 25.6 MB
  char*  bufA   = (char*)alloc((size_t)MPAD * 1024);   // 51.2 MB

  // Aliases into bufA (disjoint live ranges):
  //   xbf: written by xcast, last read by agg1; bufA next written as h1 (gemm1 out).
  //   h_e: written by ln_apply2 (hcat2 dead), read by gemm-W3 which writes h_f at bufA+0.
  short* xbf   = (short*)bufA;                              // NN x 128 bf16 (12.8 MB)
  short* h_e   = (short*)(bufA + (size_t)MPAD * 512);       // MPAD x 128 bf16 (12.8 MB)

  short* hcat1 = (short*)bufB;   // [agg1 | x]  MPAD x 256 bf16
  float* h1    = (float*)bufA;   // MPAD x 256 f32
  short* h_a   = (short*)bufB;   // MPAD x 256 bf16
  short* h_b   = (short*)bufA;   // MPAD x 512 bf16
  short* h_c   = (short*)bufB;   // MPAD x 256 bf16
  short* hcat2 = (short*)bufA;   // [agg2 | h_c] MPAD x 512 bf16
  float* h_d   = (float*)bufB;   // MPAD x 128 f32
  short* h_f   = (short*)bufA;   // MPAD x 256 bf16 (offset 0, disjoint from h_e)

  hipMemsetAsync(deg, 0, (size_t)NN * 4, stream);
  hipMemsetAsync(stats, 0, 32, stream);
  detect_kernel<<<1, 256, 0, stream>>>((const unsigned*)edge, flag);
  degree_kernel<<<(EE + 255) / 256, 256, 0, stream>>>(edge, flag, deg);
  scan_local<<<NBLK, 256, 0, stream>>>(deg, iscan, bsum);
  scan_apply<<<NBLK, 256, 0, stream>>>(iscan, bsum, offs, cursor);
  fill_kernel<<<(EE + 255) / 256, 256, 0, stream>>>(edge, flag, cursor, csr);

  xcast_kernel<<<(NN * 128 / 8 + 255) / 256, 256, 0, stream>>>(x, xbf);
  prep_all<<<1792, 256, 0, stream>>>(Wl1, Wr1, W1, W2, Wl2, Wr2, W3, W4,
                                     wc1T, w1T, w2T, wc2T, w3T, w4T);

  agg1_kernel<<<MPAD / 4, 256, 0, stream>>>(xbf, offs, csr, hcat1);
  gemm_bt<0, 0, 1, 1><<<dim3(2, MPAD / 128), 256, 0, stream>>>(hcat1, wc1T, bl1, h1, nullptr, stats, MPAD, 256, 256, NN);
  ln_apply<<<(MPAD * 256 / 4 + 255) / 256, 256, 0, stream>>>(h1, stats, ln1w, ln1b, h_a,
                                                             NN * 256, MPAD * 256, 256, 1.f / (NN * 256.f));
  gemm_bt<1, 1, 0, 0><<<dim3(4, MPAD / 128), 256, 0, stream>>>(h_a, w1T, b1, nullptr, h_b, nullptr, MPAD, 512, 256, MPAD);
  gemm_bt<1, 1, 0, 0><<<dim3(2, MPAD / 128), 256, 0, stream>>>(h_b, w2T, b2, nullptr, h_c, nullptr, MPAD, 256, 512, MPAD);
  agg2_kernel<<<MPAD / 4, 256, 0, stream>>>(h_c, offs, csr, hcat2);
  gemm_bt<0, 0, 1, 1><<<dim3(1, MPAD / 128), 256, 0, stream>>>(hcat2, wc2T, bl2, h_d, nullptr, stats + 2, MPAD, 128, 512, NN);
  ln_apply<<<(MPAD * 128 / 4 + 255) / 256, 256, 0, stream>>>(h_d, stats + 2, ln2w, ln2b, h_e,
                                                             NN * 128, MPAD * 128, 128, 1.f / (NN * 128.f));
  gemm_bt<1, 1, 0, 0><<<dim3(2, MPAD / 128), 256, 0, stream>>>(h_e, w3T, b3, nullptr, h_f, nullptr, MPAD, 256, 128, MPAD);
  gemm_bt<0, 0, 1, 0><<<dim3(1, MPAD / 128), 256, 0, stream>>>(h_f, w4T, b4, out, nullptr, nullptr, MPAD, 128, 256, NN);
}

// Round 6
// 494.818 us; speedup vs baseline: 1.4616x; 1.0485x over previous
//
#include <hip/hip_runtime.h>

#define NN   50000
#define EE   800000
#define MPAD 50048   // 391 * 128
#define NBLK ((NN + 255) / 256)   // 196

typedef __bf16 bf16x8 __attribute__((ext_vector_type(8)));
typedef float  vfloat4 __attribute__((ext_vector_type(4)));
typedef short  vshort4 __attribute__((ext_vector_type(4)));
typedef short  vshort8 __attribute__((ext_vector_type(8)));

__device__ __forceinline__ short f2bf(float f) {
  union { float f; unsigned u; } v; v.f = f;
  unsigned r = v.u + 0x7FFFu + ((v.u >> 16) & 1u);   // RNE
  return (short)(r >> 16);
}
__device__ __forceinline__ float bf2f(short h) {
  union { unsigned u; float f; } v; v.u = ((unsigned)(unsigned short)h) << 16;
  return v.f;
}

__device__ __forceinline__ void load_lds16(const short* g, short* l) {
  __builtin_amdgcn_global_load_lds(
      (__attribute__((address_space(1))) void*)(void*)g,
      (__attribute__((address_space(3))) void*)(void*)l, 16, 0, 0);
}

// ---------------- edge dtype detect (int64 vs int32) ----------------
__global__ __launch_bounds__(256) void detect_kernel(const unsigned* __restrict__ e,
                                                     int* __restrict__ flag) {
  unsigned v = 0;
  for (int i = threadIdx.x; i < 2048; i += 256) v |= e[2 * i + 1];
  for (int o = 32; o; o >>= 1) v |= (unsigned)__shfl_down((int)v, o, 64);
  __shared__ unsigned r[4];
  if ((threadIdx.x & 63) == 0) r[threadIdx.x >> 6] = v;
  __syncthreads();
  if (threadIdx.x == 0) flag[0] = ((r[0] | r[1] | r[2] | r[3]) == 0) ? 1 : 0;
}

// ---------------- CSR build ----------------
__global__ __launch_bounds__(256) void degree_kernel(const void* __restrict__ edges,
                                                     const int* __restrict__ flag,
                                                     int* __restrict__ deg) {
  int e = blockIdx.x * 256 + threadIdx.x;
  if (e >= EE) return;
  int d = flag[0] ? (int)((const long long*)edges)[EE + e] : ((const int*)edges)[EE + e];
  atomicAdd(&deg[d], 1);
}

__global__ __launch_bounds__(256) void scan_local(const int* __restrict__ deg,
                                                  int* __restrict__ iscan,
                                                  int* __restrict__ bsum) {
  __shared__ int tmp[256];
  int t = threadIdx.x;
  int i = blockIdx.x * 256 + t;
  int v = (i < NN) ? deg[i] : 0;
  tmp[t] = v;
  __syncthreads();
  int acc = v;
  for (int d = 1; d < 256; d <<= 1) {
    int u = (t >= d) ? tmp[t - d] : 0;
    __syncthreads();
    acc += u;
    tmp[t] = acc;
    __syncthreads();
  }
  if (i < NN) iscan[i] = acc - v;     // exclusive within block
  if (t == 255) bsum[blockIdx.x] = acc;
}

__global__ __launch_bounds__(256) void scan_apply(const int* __restrict__ iscan,
                                                  const int* __restrict__ bsum,
                                                  int* __restrict__ offs,
                                                  int* __restrict__ cursor) {
  __shared__ int sh[256];
  int t = threadIdx.x;
  int v = (t < NBLK) ? bsum[t] : 0;
  sh[t] = (t < (int)blockIdx.x) ? v : 0;
  __syncthreads();
  for (int d = 128; d; d >>= 1) { if (t < d) sh[t] += sh[t + d]; __syncthreads(); }
  int base = sh[0];
  __syncthreads();
  sh[t] = v;
  __syncthreads();
  for (int d = 128; d; d >>= 1) { if (t < d) sh[t] += sh[t + d]; __syncthreads(); }
  int total = sh[0];
  int i = blockIdx.x * 256 + t;
  if (i < NN) { int off = iscan[i] + base; offs[i] = off; cursor[i] = off; }
  if (blockIdx.x == gridDim.x - 1 && t == 0) offs[NN] = total;
}

__global__ __launch_bounds__(256) void fill_kernel(const void* __restrict__ edges,
                                                   const int* __restrict__ flag,
                                                   int* __restrict__ cursor,
                                                   int* __restrict__ csr) {
  int e = blockIdx.x * 256 + threadIdx.x;
  if (e >= EE) return;
  int sv, dv;
  if (flag[0]) {
    sv = (int)((const long long*)edges)[e];
    dv = (int)((const long long*)edges)[EE + e];
  } else {
    sv = ((const int*)edges)[e];
    dv = ((const int*)edges)[EE + e];
  }
  int p = atomicAdd(&cursor[dv], 1);
  csr[p] = sv;
}

// ---------------- x -> bf16 cast (NN x 128) ----------------
__global__ __launch_bounds__(256) void xcast_kernel(const float* __restrict__ x,
                                                    short* __restrict__ xbf) {
  int i = blockIdx.x * 256 + threadIdx.x;   // one per 8 elems
  if (i >= NN * 128 / 8) return;
  vfloat4 v0 = *(const vfloat4*)(x + (size_t)i * 8);
  vfloat4 v1 = *(const vfloat4*)(x + (size_t)i * 8 + 4);
  vshort8 o;
  o[0] = f2bf(v0.x); o[1] = f2bf(v0.y); o[2] = f2bf(v0.z); o[3] = f2bf(v0.w);
  o[4] = f2bf(v1.x); o[5] = f2bf(v1.y); o[6] = f2bf(v1.z); o[7] = f2bf(v1.w);
  *(vshort8*)(xbf + (size_t)i * 8) = o;
}

// ---------------- all weight preps in one launch ----------------
// dst[n*K + k] = bf16( k<K0 ? s0[k][n] : s1[k-K0][n] )
__global__ __launch_bounds__(256) void prep_all(
    const float* __restrict__ Wl1, const float* __restrict__ Wr1,
    const float* __restrict__ W1,  const float* __restrict__ W2,
    const float* __restrict__ Wl2, const float* __restrict__ Wr2,
    const float* __restrict__ W3,  const float* __restrict__ W4,
    short* __restrict__ wc1T, short* __restrict__ w1T, short* __restrict__ w2T,
    short* __restrict__ wl2T, short* __restrict__ wr2T,
    short* __restrict__ w3T,  short* __restrict__ w4T) {
  int b = blockIdx.x;
  const float *s0, *s1; short* dst; int K0, logK, Nc, base;
  if      (b <  256) { s0=Wl1; s1=Wr1; dst=wc1T; K0=128; logK=8; Nc=256; base=0;    }
  else if (b <  768) { s0=W1;  s1=W1;  dst=w1T;  K0=256; logK=8; Nc=512; base=256;  }
  else if (b < 1280) { s0=W2;  s1=W2;  dst=w2T;  K0=512; logK=9; Nc=256; base=768;  }
  else if (b < 1408) { s0=Wl2; s1=Wl2; dst=wl2T; K0=256; logK=8; Nc=128; base=1280; }
  else if (b < 1536) { s0=Wr2; s1=Wr2; dst=wr2T; K0=256; logK=8; Nc=128; base=1408; }
  else if (b < 1664) { s0=W3;  s1=W3;  dst=w3T;  K0=128; logK=7; Nc=256; base=1536; }
  else               { s0=W4;  s1=W4;  dst=w4T;  K0=256; logK=8; Nc=128; base=1664; }
  int idx = (b - base) * 256 + threadIdx.x;
  int n = idx >> logK, k = idx & ((1 << logK) - 1);
  float v = (k < K0) ? s0[(size_t)k * Nc + n] : s1[(size_t)(k - K0) * Nc + n];
  dst[idx] = f2bf(v);
}

// ---------------- mean aggregation over 128-elem bf16 rows (256 B) ----------
// 1 wave/node; 4 lane-groups of 16 gather concurrently. All __shfl run with
// the FULL wave active (R4 lesson: shfl in divergent code reads inactive
// lanes -> garbage). CONCAT=1 additionally copies the node's own src row
// into the second half of a 256-elem destination row.
template<int CONCAT>
__global__ __launch_bounds__(256) void agg_mean(const short* __restrict__ src,
                                                const int* __restrict__ offs,
                                                const int* __restrict__ csr,
                                                short* __restrict__ dst) {
  int node = blockIdx.x * 4 + (threadIdx.x >> 6);
  int lane = threadIdx.x & 63;
  if (node >= MPAD) return;
  short* row = dst + (size_t)node * (CONCAT ? 256 : 128);
  if (node >= NN) {
    if (CONCAT) *(vshort4*)(row + lane * 4) = (vshort4){0, 0, 0, 0};
    else if (lane < 32) *(vshort4*)(row + lane * 4) = (vshort4){0, 0, 0, 0};
    return;
  }
  int g = lane >> 4, sub = lane & 15;
  int e0 = offs[node], e1 = offs[node + 1];
  float a0[8] = {0, 0, 0, 0, 0, 0, 0, 0};
  float a1[8] = {0, 0, 0, 0, 0, 0, 0, 0};
  int e = e0;
  while (e < e1) {                         // wave-uniform
    int cnt = e1 - e; if (cnt > 64) cnt = 64;
    int myidx = (lane < cnt) ? csr[e + lane] : 0;
    for (int i = 0; i < cnt; i += 8) {     // wave-uniform bound
      int p0 = g + i;                      // <= 59
      int p1 = g + i + 4;                  // <= 63
      int s0 = __shfl(myidx, p0, 64);      // full wave active
      int s1 = __shfl(myidx, p1, 64);
      if (p0 < cnt) {
        vshort8 v0 = *(const vshort8*)(src + (size_t)s0 * 128 + sub * 8);
#pragma unroll
        for (int j = 0; j < 8; j++) a0[j] += bf2f(v0[j]);
      }
      if (p1 < cnt) {
        vshort8 v1 = *(const vshort8*)(src + (size_t)s1 * 128 + sub * 8);
#pragma unroll
        for (int j = 0; j < 8; j++) a1[j] += bf2f(v1[j]);
      }
    }
    e += cnt;
  }
#pragma unroll
  for (int j = 0; j < 8; j++) {
    a0[j] += a1[j];
    a0[j] += __shfl_down(a0[j], 32, 64);
    a0[j] += __shfl_down(a0[j], 16, 64);
  }
  float inv = (e1 > e0) ? 1.f / (float)(e1 - e0) : 0.f;
  if (g == 0) {
    vshort8 o;
#pragma unroll
    for (int j = 0; j < 8; j++) o[j] = f2bf(a0[j] * inv);
    *(vshort8*)(row + sub * 8) = o;
  } else if (CONCAT && g == 1) {
    *(vshort8*)(row + 128 + sub * 8) = *(const vshort8*)(src + (size_t)node * 128 + sub * 8);
  }
}

// ---------------- graph LayerNorm apply (INBF: bf16 input) ----------------
template<int INBF>
__global__ __launch_bounds__(256) void ln_apply(const void* __restrict__ h,
                                                const float* __restrict__ stats,
                                                const float* __restrict__ w,
                                                const float* __restrict__ b,
                                                short* __restrict__ out,
                                                int realElems, int totElems, int F,
                                                float invCount) {
  int base = (blockIdx.x * blockDim.x + threadIdx.x) * 4;
  if (base >= totElems) return;
  if (base >= realElems) { *(vshort4*)(out + base) = (vshort4){0,0,0,0}; return; }
  float mu  = stats[0] * invCount;
  float var = stats[1] * invCount - mu * mu;
  float rs  = rsqrtf(var + 1e-5f);
  int col = base % F;
  vfloat4 v;
  if (INBF) {
    vshort4 hv = *(const vshort4*)((const short*)h + base);
    v.x = bf2f(hv.x); v.y = bf2f(hv.y); v.z = bf2f(hv.z); v.w = bf2f(hv.w);
  } else {
    v = *(const vfloat4*)((const float*)h + base);
  }
  vshort4 o;
  o.x = f2bf(fmaxf((v.x - mu) * rs * w[col]     + b[col],     0.f));
  o.y = f2bf(fmaxf((v.y - mu) * rs * w[col + 1] + b[col + 1], 0.f));
  o.z = f2bf(fmaxf((v.z - mu) * rs * w[col + 2] + b[col + 2], 0.f));
  o.w = f2bf(fmaxf((v.w - mu) * rs * w[col + 3] + b[col + 3], 0.f));
  *(vshort4*)(out + base) = o;
}

// ---------------- GEMM: C = A(MxK,bf16) * BT(NcxK,bf16)^T + bias (+Dadd) ----
// ADDIN=1 adds bf16 Dadd[gr*Nc+gc] in the epilogue (SAGE root+agg merge).
// STATS=1 fuses graph-LN sum/sumsq (rows < Mreal, pre-ReLU) via 2 atomics/blk.
template<int RELU, int OUTBF, int BOUND, int STATS, int ADDIN>
__global__ __launch_bounds__(256) void gemm_bt(const short* __restrict__ A,
                                               const short* __restrict__ BT,
                                               const float* __restrict__ bias,
                                               float* __restrict__ Cf,
                                               short* __restrict__ Cb,
                                               const short* __restrict__ Dadd,
                                               float* __restrict__ statsOut,
                                               int M, int Nc, int K, int Mreal) {
  __shared__ short lsA[4096];   // 128 rows x 32 k
  __shared__ short lsB[4096];   // 128 n-rows x 32 k
  const int tid  = threadIdx.x;
  const int lane = tid & 63;
  const int wave = tid >> 6;
  const int wr   = (wave >> 1) << 6;
  const int wc   = (wave & 1) << 6;
  const int row0 = blockIdx.y << 7;
  const int col0 = blockIdx.x << 7;
  const int qr   = lane >> 2;
  const int qc   = (lane & 3) << 3;
  const int r16  = lane & 15;
  const int kq   = (lane >> 4) << 3;

  vfloat4 acc[4][4];
#pragma unroll
  for (int i = 0; i < 4; i++)
#pragma unroll
    for (int j = 0; j < 4; j++) acc[i][j] = (vfloat4){0.f, 0.f, 0.f, 0.f};

  const int s0 = wave * 2;
  for (int k0 = 0; k0 < K; k0 += 32) {
    __syncthreads();
#pragma unroll
    for (int t = 0; t < 2; t++) {
      int s = s0 + t;
      int trow = (s << 4) + qr;
      load_lds16(A  + (size_t)(row0 + trow) * K + k0 + qc, lsA + (s << 9) + lane * 8);
      load_lds16(BT + (size_t)(col0 + trow) * K + k0 + qc, lsB + (s << 9) + lane * 8);
    }
    __syncthreads();
    bf16x8 af[4], bfr[4];
#pragma unroll
    for (int i = 0; i < 4; i++) af[i]  = *(const bf16x8*)(lsA + ((wr + (i << 4) + r16) << 5) + kq);
#pragma unroll
    for (int j = 0; j < 4; j++) bfr[j] = *(const bf16x8*)(lsB + ((wc + (j << 4) + r16) << 5) + kq);
#pragma unroll
    for (int i = 0; i < 4; i++)
#pragma unroll
      for (int j = 0; j < 4; j++)
        acc[i][j] = __builtin_amdgcn_mfma_f32_16x16x32_bf16(af[i], bfr[j], acc[i][j], 0, 0, 0);
  }

  const int rq = (lane >> 4) << 2;
  float s = 0.f, s2 = 0.f;
#pragma unroll
  for (int i = 0; i < 4; i++) {
#pragma unroll
    for (int j = 0; j < 4; j++) {
#pragma unroll
      for (int p = 0; p < 4; p++) {
        int gr = row0 + wr + (i << 4) + rq + p;
        int gc = col0 + wc + (j << 4) + r16;
        if (BOUND && gr >= Mreal) continue;
        float v = acc[i][j][p] + bias[gc];
        if (ADDIN) v += bf2f(Dadd[(size_t)gr * Nc + gc]);
        if (STATS) { s += v; s2 += v * v; }
        if (RELU) v = fmaxf(v, 0.f);
        if (OUTBF) Cb[(size_t)gr * Nc + gc] = f2bf(v);
        else       Cf[(size_t)gr * Nc + gc] = v;
      }
    }
  }
  if (STATS) {
    for (int o2 = 32; o2; o2 >>= 1) {
      s  += __shfl_down(s,  o2, 64);
      s2 += __shfl_down(s2, o2, 64);
    }
    __shared__ float ps[8];
    if (lane == 0) { ps[wave] = s; ps[wave + 4] = s2; }
    __syncthreads();
    if (tid == 0) {
      atomicAdd(&statsOut[0], ps[0] + ps[1] + ps[2] + ps[3]);
      atomicAdd(&statsOut[1], ps[4] + ps[5] + ps[6] + ps[7]);
    }
  }
}

extern "C" void kernel_launch(void* const* d_in, const int* in_sizes, int n_in,
                              void* d_out, int out_size, void* d_ws, size_t ws_size,
                              hipStream_t stream) {
  const float* x    = (const float*)d_in[0];
  const void*  edge = d_in[1];
  const float* Wl1  = (const float*)d_in[2];
  const float* bl1  = (const float*)d_in[3];
  const float* Wr1  = (const float*)d_in[4];
  const float* ln1w = (const float*)d_in[5];
  const float* ln1b = (const float*)d_in[6];
  const float* W1   = (const float*)d_in[7];
  const float* b1   = (const float*)d_in[8];
  const float* W2   = (const float*)d_in[9];
  const float* b2   = (const float*)d_in[10];
  const float* Wl2  = (const float*)d_in[11];
  const float* bl2  = (const float*)d_in[12];
  const float* Wr2  = (const float*)d_in[13];
  const float* ln2w = (const float*)d_in[14];
  const float* ln2b = (const float*)d_in[15];
  const float* W3   = (const float*)d_in[16];
  const float* b3   = (const float*)d_in[17];
  const float* W4   = (const float*)d_in[18];
  const float* b4   = (const float*)d_in[19];
  float* out = (float*)d_out;

  char* wsp = (char*)d_ws;
  size_t o = 0;
  auto alloc = [&](size_t bytes) -> void* {
    void* p = wsp + o;
    o = (o + bytes + 255) & ~(size_t)255;
    return p;
  };
  // Footprint ~82 MB (< R2's proven-safe 94.6 MB).
  int*   flag   = (int*)alloc(4);
  int*   deg    = (int*)alloc((size_t)NN * 4);
  int*   iscan  = (int*)alloc((size_t)NN * 4);
  int*   bsum   = (int*)alloc((size_t)NBLK * 4);
  int*   offs   = (int*)alloc((size_t)(NN + 1) * 4);
  int*   cursor = (int*)alloc((size_t)NN * 4);
  int*   csr    = (int*)alloc((size_t)EE * 4);
  float* stats  = (float*)alloc(32);
  float* zbias  = (float*)alloc(512 * 4);
  short* wc1T   = (short*)alloc(256 * 256 * 2);
  short* w1T    = (short*)alloc(512 * 256 * 2);
  short* w2T    = (short*)alloc(256 * 512 * 2);
  short* wl2T   = (short*)alloc(128 * 256 * 2);
  short* wr2T   = (short*)alloc(128 * 256 * 2);
  short* w3T    = (short*)alloc(256 * 128 * 2);
  short* w4T    = (short*)alloc(128 * 256 * 2);
  char*  bufB   = (char*)alloc((size_t)MPAD * 512);    // 25.6 MB
  char*  bufA   = (char*)alloc((size_t)MPAD * 1024);   // 51.2 MB

  const size_t Q = (size_t)MPAD * 256;   // 12.8 MB quarter of bufA
  // bufA timeline: xbf@0 -> h1(bf16,25.6)@0 -> h_b(51.2)@0 ->
  //   p2@0 | a2@Q | h_d@2Q | h_e@3Q -> h_f(25.6)@0
  short* xbf   = (short*)bufA;
  short* h1    = (short*)bufA;                  // MPAD x 256 bf16
  short* h_b   = (short*)bufA;                  // MPAD x 512 bf16
  short* p2    = (short*)(bufA + Q);            // wait-free? see below
  // NOTE: p2 must not collide with h_c (bufB). Place p2 at bufA+0 is fine too,
  // but keep h_d/h_e in upper half. Layout chosen:
  p2           = (short*)bufA;                  // MPAD x 128 bf16 @0
  short* a2    = (short*)(bufA + Q);            // MPAD x 128 bf16
  short* h_d   = (short*)(bufA + 2 * Q);        // MPAD x 128 bf16
  short* h_e   = (short*)(bufA + 3 * Q);        // MPAD x 128 bf16
  short* h_f   = (short*)bufA;                  // MPAD x 256 bf16 @0 (p2/a2 dead)

  // bufB timeline: hcat1 -> h_a -> h_c (each MPAD x 256 bf16 = 25.6 MB)
  short* hcat1 = (short*)bufB;
  short* h_a   = (short*)bufB;
  short* h_c   = (short*)bufB;

  hipMemsetAsync(deg, 0, (size_t)NN * 4, stream);
  hipMemsetAsync(stats, 0, 32, stream);
  hipMemsetAsync(zbias, 0, 512 * 4, stream);
  detect_kernel<<<1, 256, 0, stream>>>((const unsigned*)edge, flag);
  degree_kernel<<<(EE + 255) / 256, 256, 0, stream>>>(edge, flag, deg);
  scan_local<<<NBLK, 256, 0, stream>>>(deg, iscan, bsum);
  scan_apply<<<NBLK, 256, 0, stream>>>(iscan, bsum, offs, cursor);
  fill_kernel<<<(EE + 255) / 256, 256, 0, stream>>>(edge, flag, cursor, csr);

  xcast_kernel<<<(NN * 128 / 8 + 255) / 256, 256, 0, stream>>>(x, xbf);
  prep_all<<<1792, 256, 0, stream>>>(Wl1, Wr1, W1, W2, Wl2, Wr2, W3, W4,
                                     wc1T, w1T, w2T, wl2T, wr2T, w3T, w4T);

  // ---- layer 1 ----
  agg_mean<1><<<MPAD / 4, 256, 0, stream>>>(xbf, offs, csr, hcat1);
  gemm_bt<0, 1, 1, 1, 0><<<dim3(2, MPAD / 128), 256, 0, stream>>>(
      hcat1, wc1T, bl1, nullptr, h1, nullptr, stats, MPAD, 256, 256, NN);
  ln_apply<1><<<(MPAD * 256 / 4 + 255) / 256, 256, 0, stream>>>(
      h1, stats, ln1w, ln1b, h_a, NN * 256, MPAD * 256, 256, 1.f / (NN * 256.f));
  gemm_bt<1, 1, 0, 0, 0><<<dim3(4, MPAD / 128), 256, 0, stream>>>(
      h_a, w1T, b1, nullptr, h_b, nullptr, nullptr, MPAD, 512, 256, MPAD);
  gemm_bt<1, 1, 0, 0, 0><<<dim3(2, MPAD / 128), 256, 0, stream>>>(
      h_b, w2T, b2, nullptr, h_c, nullptr, nullptr, MPAD, 256, 512, MPAD);

  // ---- layer 2: project-then-aggregate (agg and matmul commute) ----
  gemm_bt<0, 1, 0, 0, 0><<<dim3(1, MPAD / 128), 256, 0, stream>>>(
      h_c, wl2T, zbias, nullptr, p2, nullptr, nullptr, MPAD, 128, 256, MPAD);
  agg_mean<0><<<MPAD / 4, 256, 0, stream>>>(p2, offs, csr, a2);
  gemm_bt<0, 1, 1, 1, 1><<<dim3(1, MPAD / 128), 256, 0, stream>>>(
      h_c, wr2T, bl2, nullptr, h_d, a2, stats + 2, MPAD, 128, 256, NN);
  ln_apply<1><<<(MPAD * 128 / 4 + 255) / 256, 256, 0, stream>>>(
      h_d, stats + 2, ln2w, ln2b, h_e, NN * 128, MPAD * 128, 128, 1.f / (NN * 128.f));
  gemm_bt<1, 1, 0, 0, 0><<<dim3(2, MPAD / 128), 256, 0, stream>>>(
      h_e, w3T, b3, nullptr, h_f, nullptr, nullptr, MPAD, 256, 128, MPAD);
  gemm_bt<0, 0, 1, 0, 0><<<dim3(1, MPAD / 128), 256, 0, stream>>>(
      h_f, w4T, b4, out, nullptr, nullptr, nullptr, MPAD, 128, 256, NN);
}